// Round 2
// baseline (174.614 us; speedup 1.0000x reference)
//
#include <hip/hip_runtime.h>
#include <hip/hip_bf16.h>

typedef __attribute__((ext_vector_type(8))) short short8;
typedef __attribute__((ext_vector_type(16))) float f32x16;

#define D_DIM 128
#define G_DIM 9
#define O_DIM 128
#define K_DIM (D_DIM * G_DIM)   // 1152
#define ROWS 128                // rows per block
#define PAD 8
#define LDK (D_DIM + PAD)       // 136 shorts per LDS row (272B stride, 16B aligned)

__device__ __forceinline__ float fast_sin(float x) {
  // v_sin_f32 takes revolutions; |x| <= ~12 rad here, well inside the +-256 rev domain
  return __builtin_amdgcn_sinf(x * 0.15915494309189535f);
}

__device__ __forceinline__ short f2bf(float f) {
  // round-to-nearest-even bf16 (finite inputs only)
  unsigned u = __float_as_uint(f);
  unsigned r = (u + 0x7FFFu + ((u >> 16) & 1u)) >> 16;
  return (short)r;
}

// Prep: amplitudes (O,D,G) f32 -> Bp (O, g*128+d) bf16 ; phase (D,G) -> pt (G,D) f32
__global__ void sinekan_prep(const float* __restrict__ amp,
                             const float* __restrict__ phase,
                             short* __restrict__ Bp,
                             float* __restrict__ pt,
                             int total) {
  int i = blockIdx.x * blockDim.x + threadIdx.x;
  if (i < total) {
    int o = i / K_DIM;
    int rem = i - o * K_DIM;
    int g = rem >> 7;     // / 128
    int d = rem & 127;
    Bp[i] = f2bf(amp[(o * D_DIM + d) * G_DIM + g]);
  }
  if (i < K_DIM) {
    int g = i >> 7, d = i & 127;
    pt[i] = phase[d * G_DIM + g];
  }
}

__global__ __launch_bounds__(256, 2)
void sinekan_fused(const float* __restrict__ x,
                   const int* __restrict__ mask,      // bool -> int32 per harness spec
                   const float* __restrict__ freq,
                   const float* __restrict__ bias,
                   const float* __restrict__ lnw,
                   const float* __restrict__ lnb,
                   const short* __restrict__ Bp,
                   const float* __restrict__ pt,
                   float* __restrict__ out) {
  __shared__ short s_lds[ROWS * LDK];   // sine tile, bf16
  __shared__ short b_lds[O_DIM * LDK];  // amplitude chunk, bf16
  __shared__ float mu_s[ROWS], rs_s[ROWS], mk_s[ROWS];
  __shared__ float w_s[D_DIM], bb_s[D_DIM];

  const int tid = threadIdx.x;
  const int row0 = blockIdx.x * ROWS;

  if (tid < D_DIM) { w_s[tid] = lnw[tid]; bb_s[tid] = lnb[tid]; }
  if (tid < ROWS)  { mk_s[tid] = mask[row0 + tid] ? 1.0f : 0.0f; }

  // ---- LayerNorm stats: 2 threads per row, 64 elems each ----
  {
    int r = tid >> 1, h = tid & 1;
    const float4* xp = (const float4*)(x + (size_t)(row0 + r) * D_DIM + h * 64);
    float s = 0.f, sq = 0.f;
#pragma unroll
    for (int i = 0; i < 16; ++i) {
      float4 v = xp[i];
      s  += v.x + v.y + v.z + v.w;
      sq += v.x * v.x + v.y * v.y + v.z * v.z + v.w * v.w;
    }
    s  += __shfl_xor(s, 1, 64);
    sq += __shfl_xor(sq, 1, 64);
    if (h == 0) {
      float m = s * (1.0f / 128.0f);
      float var = sq * (1.0f / 128.0f) - m * m;
      mu_s[r] = m;
      rs_s[r] = rsqrtf(var + 1e-5f);
    }
  }
  __syncthreads();

  // ---- cache this thread's 64 xn values in registers (g-invariant) ----
  // thread footprint: rows r = sw*16 + (tid>>4), d = (tid&15)*8 .. +7
  const int dcol = (tid & 15) * 8;
  float xc[8][8];
#pragma unroll
  for (int sw = 0; sw < 8; ++sw) {
    int r = sw * 16 + (tid >> 4);
    const float4* xp = (const float4*)(x + (size_t)(row0 + r) * D_DIM + dcol);
    float4 v0 = xp[0], v1 = xp[1];
    float m = mu_s[r], rst = rs_s[r];
    float xv[8] = {v0.x, v0.y, v0.z, v0.w, v1.x, v1.y, v1.z, v1.w};
#pragma unroll
    for (int j = 0; j < 8; ++j)
      xc[sw][j] = (xv[j] - m) * rst * w_s[dcol + j] + bb_s[dcol + j];
  }

  const int lane = tid & 63;
  const int wv   = tid >> 6;          // 4 waves: 2x2 grid of 64x64 wave tiles
  const int rbase = (wv >> 1) * 64;
  const int cbase = (wv & 1) * 64;
  const int lr = lane & 31;
  const int hi = lane >> 5;

  f32x16 acc[2][2] = {};

  for (int g = 0; g < G_DIM; ++g) {
    const float fg = freq[g];

    // ---- fill sine tile: 128 rows x 128 d, 8 bf16 per task ----
#pragma unroll
    for (int sw = 0; sw < 8; ++sw) {
      int r = sw * 16 + (tid >> 4);
      const float4* pp = (const float4*)(pt + g * D_DIM + dcol);
      float4 p0 = pp[0], p1 = pp[1];
      float ph[8] = {p0.x, p0.y, p0.z, p0.w, p1.x, p1.y, p1.z, p1.w};
      short8 pk;
#pragma unroll
      for (int j = 0; j < 8; ++j)
        pk[j] = f2bf(fast_sin(fmaf(xc[sw][j], fg, ph[j])));
      *(short8*)&s_lds[r * LDK + dcol] = pk;
    }

    // ---- stage B chunk (128 o x 128 k) to LDS ----
#pragma unroll
    for (int sw = 0; sw < 8; ++sw) {
      int idx = sw * 256 + tid;
      int o  = idx >> 4;
      int un = idx & 15;
      short8 bv = *(const short8*)&Bp[o * K_DIM + g * D_DIM + un * 8];
      *(short8*)&b_lds[o * LDK + un * 8] = bv;
    }
    __syncthreads();

    // ---- MFMA over K=128 chunk: 8 iters of K=16 ----
#pragma unroll
    for (int kk = 0; kk < 8; ++kk) {
      int ko = kk * 16 + hi * 8;
      short8 a0 = *(const short8*)&s_lds[(rbase + lr)      * LDK + ko];
      short8 a1 = *(const short8*)&s_lds[(rbase + 32 + lr) * LDK + ko];
      short8 b0 = *(const short8*)&b_lds[(cbase + lr)      * LDK + ko];
      short8 b1 = *(const short8*)&b_lds[(cbase + 32 + lr) * LDK + ko];
      acc[0][0] = __builtin_amdgcn_mfma_f32_32x32x16_bf16(a0, b0, acc[0][0], 0, 0, 0);
      acc[0][1] = __builtin_amdgcn_mfma_f32_32x32x16_bf16(a0, b1, acc[0][1], 0, 0, 0);
      acc[1][0] = __builtin_amdgcn_mfma_f32_32x32x16_bf16(a1, b0, acc[1][0], 0, 0, 0);
      acc[1][1] = __builtin_amdgcn_mfma_f32_32x32x16_bf16(a1, b1, acc[1][1], 0, 0, 0);
    }
    __syncthreads();
  }

  // ---- epilogue: + bias, * mask, store f32 ----
#pragma unroll
  for (int mt = 0; mt < 2; ++mt) {
#pragma unroll
    for (int nt = 0; nt < 2; ++nt) {
      int col = cbase + nt * 32 + lr;
      float bv = bias[col];
#pragma unroll
      for (int reg = 0; reg < 16; ++reg) {
        int rit  = (reg & 3) + 8 * (reg >> 2) + 4 * hi;
        int rloc = rbase + mt * 32 + rit;
        float y = (acc[mt][nt][reg] + bv) * mk_s[rloc];
        out[(size_t)(row0 + rloc) * O_DIM + col] = y;
      }
    }
  }
}

extern "C" void kernel_launch(void* const* d_in, const int* in_sizes, int n_in,
                              void* d_out, int out_size, void* d_ws, size_t ws_size,
                              hipStream_t stream) {
  const float* x    = (const float*)d_in[0];
  const int* mk     = (const int*)d_in[1];
  const float* freq = (const float*)d_in[2];
  const float* phase= (const float*)d_in[3];
  const float* amp  = (const float*)d_in[4];
  const float* bias = (const float*)d_in[5];
  const float* lnw  = (const float*)d_in[6];
  const float* lnb  = (const float*)d_in[7];
  float* out = (float*)d_out;

  int N = in_sizes[0] / D_DIM;           // 131072 rows
  short* Bp = (short*)d_ws;              // O*K bf16 = 294912 B
  float* pt = (float*)((char*)d_ws + (size_t)O_DIM * K_DIM * sizeof(short));

  int total = O_DIM * K_DIM;
  sinekan_prep<<<(total + 255) / 256, 256, 0, stream>>>(amp, phase, Bp, pt, total);
  sinekan_fused<<<N / ROWS, 256, 0, stream>>>(x, mk, freq, bias, lnw, lnb, Bp, pt, out);
}